// Round 9
// baseline (1176.461 us; speedup 1.0000x reference)
//
#include <hip/hip_runtime.h>
#include <hip/hip_bf16.h>

// Problem: N=2048, F_IN=128, F_OUT=64
// out[j,f] = sum_{i,k} A[j,i] H[i,f] mh[i,k] H[k,f] mf[j,k],  H = X@W + b
// R10: register-wall fix. R2 = 128 VGPR + 128 AGPR = exactly the 512/SIMD
// pool at 2 waves/SIMD -> no room to pipeline frags in regs -> read window
// exposed every iter (all de-phasing attempts null). 32x32x16 f16 halves
// frag registers (24/set vs 40) and MFMA count (32/iter of ~37 SIMD-cyc),
// freeing regs for TWO frag sets -> true in-wave pipeline: read set(ks+1)
// under MFMA(ks); read next-iter ks0 from the other buffer (vmcnt-guarded)
// under ks3. Raw barrier + counted vmcnt(8): stage(t+1) never drained in
// loop. Staging/swizzle byte-identical to R2 (0-conflict verified); 32x32
// C/D mapping + epilogue from R5 (hardware-verified: R5 passed).
// Read addrs precomputed, buf via literal imm (unroll-by-2): VALU diet.

typedef __attribute__((ext_vector_type(8))) _Float16 f16x8;
typedef __attribute__((ext_vector_type(4))) _Float16 f16x4;
typedef __attribute__((ext_vector_type(16))) float f32x16;

#define N 2048
#define FOUT 64
#define FIN 128
#define NIT 512        // 16 ktiles * 32 i-steps (BI=64)

#define MFMA32(A,B,C) __builtin_amdgcn_mfma_f32_32x32x16_f16((A),(B),(C),0,0,0)
#define SB0 __builtin_amdgcn_sched_barrier(0);
#define BARS { __builtin_amdgcn_s_barrier(); SB0 }
#define VM8  { asm volatile("s_waitcnt vmcnt(8)" ::: "memory"); SB0 }
#define VM0  { asm volatile("s_waitcnt vmcnt(0)" ::: "memory"); SB0 }

#define ZERO16 ((f32x16){0.f,0.f,0.f,0.f,0.f,0.f,0.f,0.f,0.f,0.f,0.f,0.f,0.f,0.f,0.f,0.f})

__device__ __forceinline__ void gl_lds16(const _Float16* g, _Float16* l) {
    __builtin_amdgcn_global_load_lds(
        (const __attribute__((address_space(1))) void*)g,
        (__attribute__((address_space(3))) void*)l, 16, 0, 0);
}

// ---------------- prep kernels (unchanged, verified) ----------------

__global__ __launch_bounds__(256) void k_h(const float* __restrict__ X,
                                           const float* __restrict__ W,
                                           const float* __restrict__ bias,
                                           float* __restrict__ HT,
                                           _Float16* __restrict__ HTh) {
    __shared__ float Ws[FIN * FOUT];
    __shared__ float Xs[4 * FIN];
    int t = threadIdx.x;
#pragma unroll
    for (int s = 0; s < 32; ++s) Ws[t + 256 * s] = W[t + 256 * s];
    int i0 = blockIdx.x * 4;
#pragma unroll
    for (int s = 0; s < 2; ++s) { int idx = t + 256 * s; Xs[idx] = X[(size_t)i0 * FIN + idx]; }
    __syncthreads();
    int f = t & 63, il = t >> 6;
    float h = bias[f];
#pragma unroll
    for (int p = 0; p < FIN; ++p) h = fmaf(Xs[il * FIN + p], Ws[p * FOUT + f], h);
    int i = i0 + il;
    HT[f * N + i] = h;
    HTh[f * N + i] = (_Float16)h;
}

__global__ __launch_bounds__(256) void k_a2h(const float* __restrict__ A,
                                             _Float16* __restrict__ Ah) {
    int g = blockIdx.x * 256 + threadIdx.x;
    float4 v = ((const float4*)A)[g];
    f16x4 o;
    o[0] = (_Float16)v.x; o[1] = (_Float16)v.y; o[2] = (_Float16)v.z; o[3] = (_Float16)v.w;
    ((f16x4*)Ah)[g] = o;
}

__global__ __launch_bounds__(256) void k_mht(const float* __restrict__ mh,
                                             _Float16* __restrict__ mhT) {
    __shared__ float tile[64][65];
    int t = threadIdx.x;
    int bx = blockIdx.x & 31;
    int by = blockIdx.x >> 5;
#pragma unroll
    for (int s = 0; s < 16; ++s) {
        int lin = t + 256 * s;
        int r = lin >> 6, c = lin & 63;
        tile[r][c] = mh[(size_t)(by * 64 + r) * N + bx * 64 + c];
    }
    __syncthreads();
#pragma unroll
    for (int s = 0; s < 16; ++s) {
        int lin = t + 256 * s;
        int kr = lin >> 6, ic = lin & 63;
        mhT[(size_t)(bx * 64 + kr) * N + by * 64 + ic] = (_Float16)tile[ic][kr];
    }
}

// ---------------- main kernel ----------------
// grid 512 = 16 jtiles (bid>>5) * 32 fgroups (bid&31); block = 128j x 128k x 2f.
// Wave w: wj=(w&1)*64, wk=(w>>1)*64; per-wave 64x64 per f as 2x2 of 32x32.
// LDS (explicit layout, 75776B): hbuf @0 (8KB), red @8192 (2KB), tiles @10240
// (2 bufs x {A,B} x 128rows x 64 halves = 64KB). Tile row = 8 chunks of 16B,
// phys_chunk = log ^ (row&7) (R2 staging verbatim).
// 32x32x16 frags: A/B lane l: row/col = l&31, i-slots = (l>>5)*8+e; i-chunk
// for ks = ks*2+hi. C/D: col = l&31, row = (r&3)+8*(r>>2)+4*hi [R5-verified].

#define TOFF(BUFL, AB) (10240 + (BUFL) * 32768 + (AB) * 16384)

#define STAGE(IT, BUFL)                                                        \
  {                                                                            \
    int ib_ = ((IT) & 31) << 6;                                                \
    int kt_ = (IT) >> 5;                                                       \
    const _Float16* pa_ = Ah + a_base + ib_;                                   \
    const _Float16* pb_ = mhT + b_base + (size_t)kt_ * 128 * N + ib_;          \
    _Float16* la_ = (_Float16*)(lds + TOFF(BUFL, 0) + wbyte);                  \
    _Float16* lb_ = (_Float16*)(lds + TOFF(BUFL, 1) + wbyte);                  \
    _Pragma("unroll")                                                          \
    for (int c_ = 0; c_ < 4; ++c_) {                                           \
      gl_lds16(pa_ + c_ * 8 * N, la_ + c_ * 512);                              \
      gl_lds16(pb_ + c_ * 8 * N, lb_ + c_ * 512);                              \
    }                                                                          \
  }

// read frag set SUF for k-step KS from buffer BUFL; VH = h vaddr for the iter
#define READS(SUF, KS, BUFL, VH)                                               \
  xA0##SUF = *(const f16x8*)(lds + TOFF(BUFL, 0) + vA0 + chnk[KS]);            \
  xA1##SUF = *(const f16x8*)(lds + TOFF(BUFL, 0) + vA1 + chnk[KS]);            \
  xB0##SUF = *(const f16x8*)(lds + TOFF(BUFL, 1) + vB0 + chnk[KS]);            \
  xB1##SUF = *(const f16x8*)(lds + TOFF(BUFL, 1) + vB1 + chnk[KS]);            \
  xH0##SUF = *(const f16x8*)(lds + (VH) + (KS) * 32);                          \
  xH1##SUF = *(const f16x8*)(lds + (VH) + (KS) * 32 + 4096);

#define MFMA8(SUF)                                                             \
  {                                                                            \
    f16x8 p00 = xA0##SUF * xH0##SUF;                                           \
    f16x8 p10 = xA1##SUF * xH0##SUF;                                           \
    f16x8 p01 = xA0##SUF * xH1##SUF;                                           \
    f16x8 p11 = xA1##SUF * xH1##SUF;                                           \
    acc[0][0][0] = MFMA32(p00, xB0##SUF, acc[0][0][0]);                        \
    acc[0][0][1] = MFMA32(p00, xB1##SUF, acc[0][0][1]);                        \
    acc[0][1][0] = MFMA32(p10, xB0##SUF, acc[0][1][0]);                        \
    acc[0][1][1] = MFMA32(p10, xB1##SUF, acc[0][1][1]);                        \
    acc[1][0][0] = MFMA32(p01, xB0##SUF, acc[1][0][0]);                        \
    acc[1][0][1] = MFMA32(p01, xB1##SUF, acc[1][0][1]);                        \
    acc[1][1][0] = MFMA32(p11, xB0##SUF, acc[1][1][0]);                        \
    acc[1][1][1] = MFMA32(p11, xB1##SUF, acc[1][1][1]);                        \
  }

#define EPILOGUE(IT)                                                           \
  {                                                                            \
    int kb_ = (((IT) >> 5) << 7) + wk;                                         \
    float hk0[2], hk1[2];                                                      \
    _Pragma("unroll")                                                          \
    for (int tk = 0; tk < 2; ++tk) {                                           \
      int kg = kb_ + tk * 32 + l31;                                            \
      hk0[tk] = HT[f0 * N + kg];                                               \
      hk1[tk] = HT[(f0 + 1) * N + kg];                                         \
    }                                                                          \
    _Pragma("unroll")                                                          \
    for (int tj = 0; tj < 2; ++tj) {                                           \
      int jr0 = jbase + wj + tj * 32 + hi * 4;                                 \
      _Pragma("unroll")                                                        \
      for (int r = 0; r < 16; ++r) {                                           \
        int jr = jr0 + (r & 3) + 8 * (r >> 2);                                 \
        float s0 = 0.f, s1 = 0.f;                                              \
        _Pragma("unroll")                                                      \
        for (int tk = 0; tk < 2; ++tk) {                                       \
          int kg = kb_ + tk * 32 + l31;                                        \
          float m = mf[(size_t)jr * N + kg];                                   \
          s0 = fmaf(acc[0][tj][tk][r], m * hk0[tk], s0);                       \
          s1 = fmaf(acc[1][tj][tk][r], m * hk1[tk], s1);                       \
        }                                                                      \
        s0 += __shfl_xor(s0, 1);  s1 += __shfl_xor(s1, 1);                     \
        s0 += __shfl_xor(s0, 2);  s1 += __shfl_xor(s1, 2);                     \
        s0 += __shfl_xor(s0, 4);  s1 += __shfl_xor(s1, 4);                     \
        s0 += __shfl_xor(s0, 8);  s1 += __shfl_xor(s1, 8);                     \
        s0 += __shfl_xor(s0, 16); s1 += __shfl_xor(s1, 16);                    \
        if (l31 == 0) {                                                        \
          int slot = tj * 32 + (r & 3) + 8 * (r >> 2) + 4 * hi;                \
          redp[(0 * 4 + w) * 64 + slot] += s0;                                 \
          redp[(1 * 4 + w) * 64 + slot] += s1;                                 \
        }                                                                      \
      }                                                                        \
    }                                                                          \
    _Pragma("unroll")                                                          \
    for (int f_ = 0; f_ < 2; ++f_)                                             \
      _Pragma("unroll")                                                        \
      for (int a_ = 0; a_ < 2; ++a_)                                           \
        _Pragma("unroll")                                                      \
        for (int b_ = 0; b_ < 2; ++b_) acc[f_][a_][b_] = ZERO16;               \
  }

// One iteration. BUFL literal. Entering: set 'a' holds ks0 frags of IT.
#define ITER(IT, BUFL, DO_STAGE, DO_NEXT, VMW)                                 \
  {                                                                            \
    BARS                                                                       \
    if (DO_STAGE) STAGE((IT) + 1, (BUFL) ^ 1)                                  \
    VMW                                                                        \
    int vh = vhb + (((IT) & 31) << 7);                                         \
    READS(b, 1, BUFL, vh)                                                      \
    MFMA8(a)                            /* ks0 */                              \
    READS(a, 2, BUFL, vh)                                                      \
    MFMA8(b)                            /* ks1 */                              \
    READS(b, 3, BUFL, vh)                                                      \
    MFMA8(a)                            /* ks2 */                              \
    if (DO_NEXT) {                                                             \
      VM0                                                                      \
      int vh2 = vhb + ((((IT) + 1) & 31) << 7);                                \
      READS(a, 0, (BUFL) ^ 1, vh2)      /* next-iter ks0 prefetch */           \
    }                                                                          \
    MFMA8(b)                            /* ks3 */                              \
    if (((IT) & 31) == 31) EPILOGUE(IT)                                        \
  }

__global__ __launch_bounds__(256, 2) void k_main(const float* __restrict__ mf,
                                                 const float* __restrict__ HT,
                                                 const _Float16* __restrict__ HTh,
                                                 const _Float16* __restrict__ Ah,
                                                 const _Float16* __restrict__ mhT,
                                                 float* __restrict__ out) {
    __shared__ __align__(16) char lds[75776];
    float* redp = (float*)(lds + 8192);

    int t = threadIdx.x;
    int jbase = (blockIdx.x >> 5) << 7;
    int f0 = (blockIdx.x & 31) << 1;
    int w = t >> 6, lane = t & 63;
    int l31 = lane & 31, hi = lane >> 5, l7 = lane & 7;
    int wj = (w & 1) << 6, wk = (w >> 1) << 6;

    // --- stage H rows (once) into hbuf @0 ---
#pragma unroll
    for (int s = 0; s < 2; ++s) {
        int idx = t + 256 * s;                // fi=idx>>8, chunk=idx&255
        ((f16x8*)lds)[idx] = *(const f16x8*)&HTh[(size_t)(f0 + (idx >> 8)) * N + (idx & 255) * 8];
    }
    redp[t] = 0.f;
    redp[t + 256] = 0.f;

    // --- staging source offsets (R2 verbatim) ---
    int lrow = lane >> 3;                      // row within 8-row call
    int lchunk = (lane & 7) ^ lrow;            // logical chunk (XOR swizzle)
    int a_base = (jbase + w * 32 + lrow) * N + lchunk * 8;
    int b_base = (w * 32 + lrow) * N + lchunk * 8;   // + ktile*128*N per ktile
    int wbyte = w * 4096;                      // (w*32 rows)*64 halves*2B

    // --- hoisted fragment read offsets (bytes within a tile) ---
    int vA0 = (wj + 0 + l31) * 128;
    int vA1 = (wj + 32 + l31) * 128;
    int vB0 = (wk + 0 + l31) * 128;
    int vB1 = (wk + 32 + l31) * 128;
    int chnk[4];
#pragma unroll
    for (int ks = 0; ks < 4; ++ks) chnk[ks] = ((ks * 2 + hi) ^ l7) * 16;
    int vhb = hi * 16;                         // + fi*4096 + ks*32 via imm

    f16x8 xA0a, xA1a, xB0a, xB1a, xH0a, xH1a;
    f16x8 xA0b, xA1b, xB0b, xB1b, xH0b, xH1b;

    f32x16 acc[2][2][2];
#pragma unroll
    for (int f_ = 0; f_ < 2; ++f_)
#pragma unroll
        for (int a_ = 0; a_ < 2; ++a_)
#pragma unroll
            for (int b_ = 0; b_ < 2; ++b_) acc[f_][a_][b_] = ZERO16;

    // --- prologue: stage(0) -> buf0; full drain once; read ks0(0) ---
    STAGE(0, 0)
    __syncthreads();
    READS(a, 0, 0, vhb)

    // --- main loop: 2 iters/trip (buf literal), iters 0..509 ---
    for (int tp = 0; tp < 255; ++tp) {
        ITER(tp * 2,     0, 1, 1, VM8)
        ITER(tp * 2 + 1, 1, 1, 1, VM8)
    }
    // iter 510 (buf0): stages 511, prefetches its ks0
    ITER(510, 0, 1, 1, VM8)
    // iter 511 (buf1): no stage, no next; drain stage(511)
    ITER(511, 1, 0, 0, VM0)

    // --- cross-wave reduce + store ---
    __syncthreads();
    if (t < 128) {
        int j = t;
#pragma unroll
        for (int fi = 0; fi < 2; ++fi) {
            float v = (j < 64) ? (redp[(fi * 4 + 0) * 64 + j] + redp[(fi * 4 + 2) * 64 + j])
                               : (redp[(fi * 4 + 1) * 64 + j - 64] + redp[(fi * 4 + 3) * 64 + j - 64]);
            out[(size_t)(jbase + j) * FOUT + f0 + fi] = v;
        }
    }
}

// ---------------- launch ----------------
extern "C" void kernel_launch(void* const* d_in, const int* in_sizes, int n_in,
                              void* d_out, int out_size, void* d_ws, size_t ws_size,
                              hipStream_t stream) {
    const float* X    = (const float*)d_in[0];
    const float* A    = (const float*)d_in[1];
    const float* mf   = (const float*)d_in[2];
    const float* mh   = (const float*)d_in[3];
    const float* W    = (const float*)d_in[4];
    const float* bias = (const float*)d_in[5];
    float* out = (float*)d_out;

    float*    HT  = (float*)d_ws;
    _Float16* HTh = (_Float16*)((char*)d_ws + 524288);
    _Float16* Ah  = (_Float16*)((char*)d_ws + 1048576);
    _Float16* mhT = (_Float16*)((char*)d_ws + 1048576 + 8388608);

    k_h<<<N / 4, 256, 0, stream>>>(X, W, bias, HT, HTh);
    k_a2h<<<(N * N / 4) / 256, 256, 0, stream>>>(A, Ah);
    k_mht<<<(N / 64) * (N / 64), 256, 0, stream>>>(mh, mhT);
    k_main<<<16 * 32, 256, 0, stream>>>(mf, HT, HTh, Ah, mhT, out);
}